// Round 1
// baseline (794.719 us; speedup 1.0000x reference)
//
#include <hip/hip_runtime.h>
#include <cstdint>

#define HD 64
#define NNODES 200000
#define NS_ELEMS (NNODES * HD)          // 12,800,000

typedef short bf8 __attribute__((ext_vector_type(8)));
typedef short s2v __attribute__((ext_vector_type(2)));
typedef float f32x4 __attribute__((ext_vector_type(4)));

// ---- order-preserving float <-> uint for atomicMax ----
__device__ __forceinline__ unsigned enc_f32(float f) {
    unsigned u = __float_as_uint(f);
    return (u & 0x80000000u) ? ~u : (u | 0x80000000u);
}
__device__ __forceinline__ float dec_f32(unsigned v) {
    return (v & 0x80000000u) ? __uint_as_float(v & 0x7fffffffu)
                             : __uint_as_float(~v);
}

// RNE float -> bf16 bits, and back
__device__ __forceinline__ ushort f2bf(float f) {
    unsigned u = __float_as_uint(f);
    return (ushort)((u + 0x7fffu + ((u >> 16) & 1u)) >> 16);
}
__device__ __forceinline__ float bf2f(ushort b) {
    return __uint_as_float(((unsigned)b) << 16);
}

// ---- packed 2x bf16 atomic add (fallback path only) ----
__device__ __forceinline__ void atom_pk_add_bf16(ushort* p, ushort lo, ushort hi) {
    s2v v; v[0] = (short)lo; v[1] = (short)hi;
#if __has_builtin(__builtin_amdgcn_flat_atomic_fadd_v2bf16)
    (void)__builtin_amdgcn_flat_atomic_fadd_v2bf16((s2v*)p, v);
#elif __has_builtin(__builtin_amdgcn_global_atomic_fadd_v2bf16)
    (void)__builtin_amdgcn_global_atomic_fadd_v2bf16(
        (__attribute__((address_space(1))) s2v*)p, v);
#else
    unsigned* a = (unsigned*)p;
    unsigned old = *a, assumed;
    do {
        assumed = old;
        float f0 = bf2f((ushort)(assumed & 0xffffu)) + bf2f(lo);
        float f1 = bf2f((ushort)(assumed >> 16))     + bf2f(hi);
        unsigned nv = (unsigned)f2bf(f0) | ((unsigned)f2bf(f1) << 16);
        old = atomicCAS(a, assumed, nv);
    } while (old != assumed);
#endif
}

// ================= prep: ns fp32->bf16; weights fp32 -> bf16 frag-linear =====
struct PrepArgs {
    const float* src[8];
    ushort*      dst[8];
    int din[8], dout[8], nelem[8];
};

__global__ __launch_bounds__(256) void prep_kernel(
    const float* __restrict__ ns, ushort* __restrict__ ns16, PrepArgs pa, int total)
{
    int stride = gridDim.x * 256;
    for (int i = blockIdx.x * 256 + threadIdx.x; i < total; i += stride) {
        if (i < NS_ELEMS) { ns16[i] = f2bf(ns[i]); continue; }
        int e = i - NS_ELEMS;
        #pragma unroll
        for (int m = 0; m < 8; m++) {
            if (e < pa.nelem[m]) {
                int din = pa.din[m], dout = pa.dout[m];
                int n = e / din, k = e - n * din;
                pa.dst[m][(k >> 5) * dout * 32 + n * 32 + (k & 31)] = f2bf(pa.src[m][e]);
                e = 0x7fffffff;
            } else {
                e -= pa.nelem[m];
            }
        }
    }
}

// ================= CSR build: hist -> scan -> fill ==========================
__global__ __launch_bounds__(256) void hist_kernel(
    const int* __restrict__ i0, const int* __restrict__ i1, const int* __restrict__ i2,
    int b1e, int b2e, int total, int* __restrict__ cnt)
{
    int s = blockIdx.x * 256 + threadIdx.x;
    if (s >= total) return;
    int node = (s < b1e) ? i0[s] : (s < b2e ? i1[s - b1e] : i2[s - b2e]);
    atomicAdd(&cnt[node], 1);
}

__global__ __launch_bounds__(256) void scan1_kernel(
    const int* __restrict__ cnt, int* __restrict__ startv,
    int* __restrict__ partials, int n)
{
    __shared__ int wsum[4];
    int i = blockIdx.x * 256 + threadIdx.x;
    int v = (i < n) ? cnt[i] : 0;
    int lane = threadIdx.x & 63, wid = threadIdx.x >> 6;
    int x = v;
    #pragma unroll
    for (int off = 1; off < 64; off <<= 1) {
        int y = __shfl_up(x, off);
        if (lane >= off) x += y;
    }
    if (lane == 63) wsum[wid] = x;
    __syncthreads();
    int woff = 0;
    for (int w = 0; w < wid; w++) woff += wsum[w];
    int incl = x + woff;
    if (i < n) startv[i] = incl - v;              // block-local exclusive
    if (threadIdx.x == 255) partials[blockIdx.x] = incl;
}

__global__ __launch_bounds__(1024) void scan2_kernel(int* __restrict__ partials, int nb)
{
    __shared__ int sh[1024];
    int t = threadIdx.x;
    int orig = (t < nb) ? partials[t] : 0;
    sh[t] = orig;
    __syncthreads();
    for (int off = 1; off < 1024; off <<= 1) {
        int v = (t >= off) ? sh[t - off] : 0;
        __syncthreads();
        sh[t] += v;
        __syncthreads();
    }
    if (t < nb) partials[t] = sh[t] - orig;       // exclusive
}

__global__ __launch_bounds__(256) void scan3_kernel(
    int* __restrict__ startv, int* __restrict__ offv,
    const int* __restrict__ partials, int n, int total)
{
    int i = blockIdx.x * 256 + threadIdx.x;
    if (i < n) {
        int s = startv[i] + partials[blockIdx.x];
        startv[i] = s;
        offv[i] = s;
    }
    if (i == 0) startv[n] = total;
}

__global__ __launch_bounds__(256) void fill_kernel(
    const int* __restrict__ i0, const int* __restrict__ i1, const int* __restrict__ i2,
    int b1e, int b2e, int total, int* __restrict__ offv, int* __restrict__ adj)
{
    int s = blockIdx.x * 256 + threadIdx.x;
    if (s >= total) return;
    int node = (s < b1e) ? i0[s] : (s < b2e ? i1[s - b1e] : i2[s - b2e]);
    int p = atomicAdd(&offv[node], 1);
    adj[p] = s;
}

// ================= one MFMA dense layer over a 32-row LDS tile ===============
template<int DIN, int DOUT, int NT, int PDIN>
__device__ __forceinline__ void mfma_layer(
    const ushort* __restrict__ WT, const float* __restrict__ bias,
    const ushort* __restrict__ Xs, int wave, int lane, f32x4 acc[2][NT])
{
    constexpr int KS = DIN / 32;
    const int q = lane >> 4, ln = lane & 15;
    const int n0 = wave * NT * 16;
    bf8 bf[NT][KS];
    #pragma unroll
    for (int nt = 0; nt < NT; nt++) {
        float bv = bias[n0 + nt * 16 + ln];
        acc[0][nt] = f32x4{bv, bv, bv, bv};
        acc[1][nt] = f32x4{bv, bv, bv, bv};
        #pragma unroll
        for (int ks = 0; ks < KS; ks++)
            bf[nt][ks] = *(const bf8*)(WT + (size_t)ks * DOUT * 32
                                          + (n0 + nt * 16 + ln) * 32 + q * 8);
    }
    #pragma unroll
    for (int mt = 0; mt < 2; mt++) {
        bf8 af[KS];
        #pragma unroll
        for (int ks = 0; ks < KS; ks++)
            af[ks] = *(const bf8*)(Xs + (mt * 16 + ln) * PDIN + ks * 32 + q * 8);
        #pragma unroll
        for (int ks = 0; ks < KS; ks++)
            #pragma unroll
            for (int nt = 0; nt < NT; nt++)
                acc[mt][nt] = __builtin_amdgcn_mfma_f32_16x16x32_bf16(
                    af[ks], bf[nt][ks], acc[mt][nt], 0, 0, 0);
    }
}

// ================= relation kernel: NEW (linear O writes, no atomics) ========
template<int A>
__global__ __launch_bounds__(256) void rel_mfma_w(
    const ushort* __restrict__ ns16, const int* __restrict__ idx,
    const ushort* __restrict__ wt1, const float* __restrict__ b1,
    const ushort* __restrict__ wt2, const float* __restrict__ b2,
    ushort* __restrict__ O, unsigned* __restrict__ Mword)
{
    constexpr int D  = A * HD;
    constexpr int PD = D + 8;
    constexpr int NT = D / 64;
    __shared__ __align__(16) ushort Xs[32 * PD];
    __shared__ __align__(16) ushort Hs[32 * PD];
    __shared__ float wred[4];

    const int tid = threadIdx.x;
    const int t0  = blockIdx.x * 32;

    for (int lin = tid; lin < 32 * A * 8; lin += 256) {
        int slot = lin >> 3, part = lin & 7;
        int node = idx[t0 * A + slot];
        int row = slot / A, sub = slot - row * A;
        *(uint4*)(Xs + row * PD + sub * 64 + part * 8) =
            *(const uint4*)(ns16 + (size_t)node * HD + part * 8);
    }
    __syncthreads();

    const int wave = tid >> 6, lane = tid & 63;
    const int q = lane >> 4, ln = lane & 15, n0 = wave * NT * 16;

    f32x4 acc[2][NT];
    mfma_layer<D, D, NT, PD>(wt1, b1, Xs, wave, lane, acc);
    #pragma unroll
    for (int mt = 0; mt < 2; mt++)
        #pragma unroll
        for (int nt = 0; nt < NT; nt++)
            #pragma unroll
            for (int r = 0; r < 4; r++)
                Hs[(mt * 16 + q * 4 + r) * PD + n0 + nt * 16 + ln] =
                    f2bf(fmaxf(acc[mt][nt][r], 0.f));
    __syncthreads();
    mfma_layer<D, D, NT, PD>(wt2, b2, Hs, wave, lane, acc);

    // epilogue: linear coalesced writes of exp(8*o) into O[slot][feat]
    float m = -3.0e38f;
    const bool even = (ln & 1) == 0;
    #pragma unroll
    for (int mt = 0; mt < 2; mt++)
        #pragma unroll
        for (int nt = 0; nt < NT; nt++) {
            int colg = n0 + nt * 16 + ln;
            int sub  = colg >> 6;
            int featp = (colg & 63) & ~1;          // even feat of the pair
            float e[4], p[4];
            #pragma unroll
            for (int r = 0; r < 4; r++) {
                float o = acc[mt][nt][r];
                m = fmaxf(m, o);
                e[r] = __expf(8.f * o);
            }
            #pragma unroll
            for (int r = 0; r < 4; r++) p[r] = __shfl_xor(e[r], 1);
            #pragma unroll
            for (int j = 0; j < 2; j++) {
                int r   = even ? j : (2 + j);
                int row = mt * 16 + q * 4 + r;
                size_t slot = (size_t)(t0 + row) * A + sub;
                unsigned lo = even ? (unsigned)f2bf(e[r]) : (unsigned)f2bf(p[r]);
                unsigned hi = even ? (unsigned)f2bf(p[r]) : (unsigned)f2bf(e[r]);
                *(unsigned*)(O + slot * HD + featp) = lo | (hi << 16);
            }
        }
    #pragma unroll
    for (int off = 32; off; off >>= 1) m = fmaxf(m, __shfl_xor(m, off));
    if (lane == 0) wred[wave] = m;
    __syncthreads();
    if (tid == 0)
        atomicMax(Mword, enc_f32(fmaxf(fmaxf(wred[0], wred[1]),
                                       fmaxf(wred[2], wred[3]))));
}

// ================= relation kernel: OLD (atomic scatter, fallback) ===========
template<int A>
__global__ __launch_bounds__(256) void rel_mfma(
    const ushort* __restrict__ ns16, const int* __restrict__ idx,
    const ushort* __restrict__ wt1, const float* __restrict__ b1,
    const ushort* __restrict__ wt2, const float* __restrict__ b2,
    ushort* __restrict__ S16, unsigned* __restrict__ Mword)
{
    constexpr int D  = A * HD;
    constexpr int PD = D + 8;
    constexpr int NT = D / 64;
    __shared__ __align__(16) ushort Xs[32 * PD];
    __shared__ __align__(16) ushort Hs[32 * PD];
    __shared__ int Is[32 * A];
    __shared__ float wred[4];

    const int tid = threadIdx.x;
    const int t0  = blockIdx.x * 32;

    if (tid < 32 * A) Is[tid] = idx[t0 * A + tid];
    for (int lin = tid; lin < 32 * A * 8; lin += 256) {
        int slot = lin >> 3, part = lin & 7;
        int node = idx[t0 * A + slot];
        int row = slot / A, sub = slot - row * A;
        *(uint4*)(Xs + row * PD + sub * 64 + part * 8) =
            *(const uint4*)(ns16 + (size_t)node * HD + part * 8);
    }
    __syncthreads();

    const int wave = tid >> 6, lane = tid & 63;
    const int q = lane >> 4, ln = lane & 15, n0 = wave * NT * 16;

    f32x4 acc[2][NT];
    mfma_layer<D, D, NT, PD>(wt1, b1, Xs, wave, lane, acc);
    #pragma unroll
    for (int mt = 0; mt < 2; mt++)
        #pragma unroll
        for (int nt = 0; nt < NT; nt++)
            #pragma unroll
            for (int r = 0; r < 4; r++)
                Hs[(mt * 16 + q * 4 + r) * PD + n0 + nt * 16 + ln] =
                    f2bf(fmaxf(acc[mt][nt][r], 0.f));
    __syncthreads();
    mfma_layer<D, D, NT, PD>(wt2, b2, Hs, wave, lane, acc);

    float m = -3.0e38f;
    const bool even = (ln & 1) == 0;
    #pragma unroll
    for (int mt = 0; mt < 2; mt++)
        #pragma unroll
        for (int nt = 0; nt < NT; nt++) {
            int colg = n0 + nt * 16 + ln;
            int sub  = colg >> 6;
            int featp = (colg & 63) & ~1;
            float e[4], p[4];
            #pragma unroll
            for (int r = 0; r < 4; r++) {
                float o = acc[mt][nt][r];
                m = fmaxf(m, o);
                e[r] = __expf(8.f * o);
            }
            #pragma unroll
            for (int r = 0; r < 4; r++) p[r] = __shfl_xor(e[r], 1);
            #pragma unroll
            for (int j = 0; j < 2; j++) {
                int r   = even ? j : (2 + j);
                int row = mt * 16 + q * 4 + r;
                int node = Is[row * A + sub];
                ushort lo = even ? f2bf(e[r]) : f2bf(p[r]);
                ushort hi = even ? f2bf(p[r]) : f2bf(e[r]);
                atom_pk_add_bf16(S16 + (size_t)node * HD + featp, lo, hi);
            }
        }
    #pragma unroll
    for (int off = 32; off; off >>= 1) m = fmaxf(m, __shfl_xor(m, off));
    if (lane == 0) wred[wave] = m;
    __syncthreads();
    if (tid == 0)
        atomicMax(Mword, enc_f32(fmaxf(fmaxf(wred[0], wred[1]),
                                       fmaxf(wred[2], wred[3]))));
}

// ================= update kernel: NEW (CSR segmented reduce + MFMA) ==========
__global__ __launch_bounds__(256) void update_csr(
    const float* __restrict__ ns, const ushort* __restrict__ O,
    const int* __restrict__ startv, const int* __restrict__ adj,
    const unsigned* __restrict__ Mword,
    const ushort* __restrict__ wt1, const float* __restrict__ b1,
    const ushort* __restrict__ wt2, const float* __restrict__ b2,
    float* __restrict__ out)
{
    constexpr int D = 128, PD = D + 8;
    constexpr int ACAP = 2048;
    __shared__ __align__(16) ushort Xs[32 * PD];
    __shared__ __align__(16) ushort Hs[32 * PD];
    __shared__ int adjLds[ACAP];

    const int tid = threadIdx.x;
    const int r0  = blockIdx.x * 32;
    const float corr = 1e-16f * __expf(8.f * dec_f32(*Mword));

    const int segbase = startv[r0];
    const int seglen  = startv[r0 + 32] - segbase;
    for (int k = tid; k < seglen && k < ACAP; k += 256)
        adjLds[k] = adj[segbase + k];

    // ns half: rows 0..31, cols 64..127
    for (int lin = tid; lin < 32 * 8; lin += 256) {
        int row = lin >> 3, p8 = (lin & 7) * 8;
        const float* src = ns + (size_t)(r0 + row) * HD + p8;
        float4 a = *(const float4*)src;
        float4 b = *(const float4*)(src + 4);
        ushort tmp[8] = { f2bf(a.x), f2bf(a.y), f2bf(a.z), f2bf(a.w),
                          f2bf(b.x), f2bf(b.y), f2bf(b.z), f2bf(b.w) };
        *(uint4*)(Xs + row * PD + 64 + p8) = *(uint4*)tmp;
    }
    __syncthreads();

    // segmented reduce: thread t owns node row (t>>3), feats (t&7)*8 .. +8
    {
        const int row = tid >> 3, f0 = (tid & 7) * 8;
        const int s0 = startv[r0 + row] - segbase;
        const int s1 = startv[r0 + row + 1] - segbase;
        float sum[8] = {0.f, 0.f, 0.f, 0.f, 0.f, 0.f, 0.f, 0.f};
        int k = s0;
        for (; k + 1 < s1; k += 2) {
            int sa = (k     < ACAP) ? adjLds[k]     : adj[segbase + k];
            int sb = (k + 1 < ACAP) ? adjLds[k + 1] : adj[segbase + k + 1];
            ushort ra[8], rb[8];
            *(uint4*)ra = *(const uint4*)(O + (size_t)sa * HD + f0);
            *(uint4*)rb = *(const uint4*)(O + (size_t)sb * HD + f0);
            #pragma unroll
            for (int j = 0; j < 8; j++) sum[j] += bf2f(ra[j]) + bf2f(rb[j]);
        }
        if (k < s1) {
            int sa = (k < ACAP) ? adjLds[k] : adj[segbase + k];
            ushort ra[8];
            *(uint4*)ra = *(const uint4*)(O + (size_t)sa * HD + f0);
            #pragma unroll
            for (int j = 0; j < 8; j++) sum[j] += bf2f(ra[j]);
        }
        ushort tmp[8];
        #pragma unroll
        for (int j = 0; j < 8; j++)
            tmp[j] = f2bf(0.125f * __logf(sum[j] + corr));
        *(uint4*)(Xs + row * PD + f0) = *(uint4*)tmp;
    }
    __syncthreads();

    const int wave = tid >> 6, lane = tid & 63;
    const int q = lane >> 4, ln = lane & 15;

    f32x4 acc[2][2];
    mfma_layer<128, 128, 2, PD>(wt1, b1, Xs, wave, lane, acc);
    #pragma unroll
    for (int mt = 0; mt < 2; mt++)
        #pragma unroll
        for (int nt = 0; nt < 2; nt++)
            #pragma unroll
            for (int r = 0; r < 4; r++)
                Hs[(mt * 16 + q * 4 + r) * PD + wave * 32 + nt * 16 + ln] =
                    f2bf(fmaxf(acc[mt][nt][r], 0.f));
    __syncthreads();

    f32x4 acc2[2][1];
    mfma_layer<128, 64, 1, PD>(wt2, b2, Hs, wave, lane, acc2);
    #pragma unroll
    for (int mt = 0; mt < 2; mt++)
        #pragma unroll
        for (int r = 0; r < 4; r++)
            out[(size_t)(r0 + mt * 16 + q * 4 + r) * HD + wave * 16 + ln] =
                acc2[mt][0][r];
}

// ================= update kernel: OLD (bf16-accum read, fallback) ============
__global__ __launch_bounds__(256) void update_mfma(
    const float* __restrict__ ns, const ushort* __restrict__ S16,
    const unsigned* __restrict__ Mword,
    const ushort* __restrict__ wt1, const float* __restrict__ b1,
    const ushort* __restrict__ wt2, const float* __restrict__ b2,
    float* __restrict__ out)
{
    constexpr int D = 128, PD = D + 8;
    __shared__ __align__(16) ushort Xs[32 * PD];
    __shared__ __align__(16) ushort Hs[32 * PD];

    const int tid = threadIdx.x;
    const int r0  = blockIdx.x * 32;
    const float corr = 1e-16f * __expf(8.f * dec_f32(*Mword));

    for (int lin = tid; lin < 32 * 16; lin += 256) {
        int row = lin >> 4, c8 = (lin & 15) * 8;
        ushort tmp[8];
        if (c8 < 64) {
            ushort raw[8];
            *(uint4*)raw = *(const uint4*)(S16 + (size_t)(r0 + row) * HD + c8);
            #pragma unroll
            for (int j = 0; j < 8; j++)
                tmp[j] = f2bf(0.125f * __logf(bf2f(raw[j]) + corr));
        } else {
            #pragma unroll
            for (int j = 0; j < 8; j++)
                tmp[j] = f2bf(ns[(size_t)(r0 + row) * HD + (c8 - 64) + j]);
        }
        *(uint4*)(Xs + row * PD + c8) = *(uint4*)tmp;
    }
    __syncthreads();

    const int wave = tid >> 6, lane = tid & 63;
    const int q = lane >> 4, ln = lane & 15;

    f32x4 acc[2][2];
    mfma_layer<128, 128, 2, PD>(wt1, b1, Xs, wave, lane, acc);
    #pragma unroll
    for (int mt = 0; mt < 2; mt++)
        #pragma unroll
        for (int nt = 0; nt < 2; nt++)
            #pragma unroll
            for (int r = 0; r < 4; r++)
                Hs[(mt * 16 + q * 4 + r) * PD + wave * 32 + nt * 16 + ln] =
                    f2bf(fmaxf(acc[mt][nt][r], 0.f));
    __syncthreads();

    f32x4 acc2[2][1];
    mfma_layer<128, 64, 1, PD>(wt2, b2, Hs, wave, lane, acc2);
    #pragma unroll
    for (int mt = 0; mt < 2; mt++)
        #pragma unroll
        for (int r = 0; r < 4; r++)
            out[(size_t)(r0 + mt * 16 + q * 4 + r) * HD + wave * 16 + ln] =
                acc2[mt][0][r];
}

// ================= host =====================================================
extern "C" void kernel_launch(void* const* d_in, const int* in_sizes, int n_in,
                              void* d_out, int out_size, void* d_ws, size_t ws_size,
                              hipStream_t stream)
{
    const float* ns   = (const float*)d_in[0];
    const int*   idx0 = (const int*)d_in[1];
    const int*   idx1 = (const int*)d_in[2];
    const int*   idx2 = (const int*)d_in[3];
    const float* W[8] = { (const float*)d_in[4],  (const float*)d_in[6],
                          (const float*)d_in[8],  (const float*)d_in[10],
                          (const float*)d_in[12], (const float*)d_in[14],
                          (const float*)d_in[16], (const float*)d_in[18] };
    const float* B[8] = { (const float*)d_in[5],  (const float*)d_in[7],
                          (const float*)d_in[9],  (const float*)d_in[11],
                          (const float*)d_in[13], (const float*)d_in[15],
                          (const float*)d_in[17], (const float*)d_in[19] };
    static const int DIN[8]  = {128,128,128,128,192,192,128,128};
    static const int DOUT[8] = {128,128,128,128,192,192,128, 64};

    const int n0f = in_sizes[1];          // 600000 flat ints
    const int n1f = in_sizes[2];          // 600000
    const int n2f = in_sizes[3];          // 600000
    const int TOT = n0f + n1f + n2f;      // 1,800,000
    const int T0 = n0f / 2, T1 = n1f / 2, T2 = n2f / 3;

    size_t wtot = 0;
    for (int m = 0; m < 8; m++) wtot += (size_t)DIN[m] * DOUT[m];   // 360,448

    // ---- new-path workspace layout ----
    size_t oO     = 0;
    size_t oNs    = oO  + (size_t)TOT * HD * 2;                     // O: 230.4 MB
    size_t oWT    = oNs + (size_t)NS_ELEMS * 2;                     // ns16: 25.6 MB
    size_t oAdj   = oWT + ((wtot * 2 + 255) & ~(size_t)255);
    size_t oStart = oAdj + (((size_t)TOT * 4 + 255) & ~(size_t)255);
    size_t oOff   = oStart + (((size_t)(NNODES + 1) * 4 + 255) & ~(size_t)255);
    size_t oPart  = oOff + (size_t)NNODES * 4;
    size_t oCnt   = oPart + 4096;
    size_t oMw    = oCnt + (size_t)NNODES * 4;
    size_t NEED   = oMw + 64;

    if (ws_size >= NEED) {
        // ================= CSR / linear-write path =================
        ushort*   O     = (ushort*)d_ws;
        ushort*   ns16  = (ushort*)((char*)d_ws + oNs);
        ushort*   WTb   = (ushort*)((char*)d_ws + oWT);
        int*      adj   = (int*)((char*)d_ws + oAdj);
        int*      start = (int*)((char*)d_ws + oStart);
        int*      offp  = (int*)((char*)d_ws + oOff);
        int*      part  = (int*)((char*)d_ws + oPart);
        int*      cnt   = (int*)((char*)d_ws + oCnt);
        unsigned* Mw    = (unsigned*)((char*)d_ws + oMw);

        PrepArgs pa;
        int total = NS_ELEMS;
        ushort* wt[8];
        {
            ushort* p = WTb;
            for (int m = 0; m < 8; m++) {
                pa.src[m] = W[m];
                pa.dst[m] = p;  wt[m] = p;
                pa.din[m] = DIN[m]; pa.dout[m] = DOUT[m];
                pa.nelem[m] = DIN[m] * DOUT[m];
                p += pa.nelem[m];
                total += pa.nelem[m];
            }
        }

        hipMemsetAsync((char*)d_ws + oCnt, 0, (size_t)NNODES * 4 + 64, stream);
        prep_kernel<<<4096, 256, 0, stream>>>(ns, ns16, pa, total);

        const int NB   = (NNODES + 255) / 256;
        const int gTOT = (TOT + 255) / 256;
        hist_kernel<<<gTOT, 256, 0, stream>>>(idx0, idx1, idx2, n0f, n0f + n1f, TOT, cnt);
        scan1_kernel<<<NB, 256, 0, stream>>>(cnt, start, part, NNODES);
        scan2_kernel<<<1, 1024, 0, stream>>>(part, NB);
        scan3_kernel<<<NB, 256, 0, stream>>>(start, offp, part, NNODES, TOT);
        fill_kernel<<<gTOT, 256, 0, stream>>>(idx0, idx1, idx2, n0f, n0f + n1f, TOT, offp, adj);

        rel_mfma_w<2><<<T0 / 32, 256, 0, stream>>>(
            ns16, idx0, wt[0], B[0], wt[1], B[1], O, Mw);
        rel_mfma_w<2><<<T1 / 32, 256, 0, stream>>>(
            ns16, idx1, wt[2], B[2], wt[3], B[3], O + (size_t)n0f * HD, Mw);
        rel_mfma_w<3><<<T2 / 32, 256, 0, stream>>>(
            ns16, idx2, wt[4], B[4], wt[5], B[5], O + (size_t)(n0f + n1f) * HD, Mw);

        update_csr<<<NNODES / 32, 256, 0, stream>>>(
            ns, O, start, adj, Mw, wt[6], B[6], wt[7], B[7], (float*)d_out);
    } else {
        // ================= fallback: previous atomic path =================
        ushort*   S16  = (ushort*)d_ws;
        size_t    offM = (size_t)NNODES * HD * sizeof(ushort);
        unsigned* Mw   = (unsigned*)((char*)d_ws + offM);
        ushort*   ns16 = (ushort*)((char*)d_ws + offM + 64);
        ushort*   WTb  = ns16 + (size_t)NS_ELEMS;

        PrepArgs pa;
        int total = NS_ELEMS;
        ushort* wt[8];
        {
            ushort* p = WTb;
            for (int m = 0; m < 8; m++) {
                pa.src[m] = W[m];
                pa.dst[m] = p;  wt[m] = p;
                pa.din[m] = DIN[m]; pa.dout[m] = DOUT[m];
                pa.nelem[m] = DIN[m] * DOUT[m];
                p += pa.nelem[m];
                total += pa.nelem[m];
            }
        }

        hipMemsetAsync(d_ws, 0, offM + 64, stream);
        prep_kernel<<<4096, 256, 0, stream>>>(ns, ns16, pa, total);

        rel_mfma<2><<<T0 / 32, 256, 0, stream>>>(ns16, idx0, wt[0], B[0], wt[1], B[1], S16, Mw);
        rel_mfma<2><<<T1 / 32, 256, 0, stream>>>(ns16, idx1, wt[2], B[2], wt[3], B[3], S16, Mw);
        rel_mfma<3><<<T2 / 32, 256, 0, stream>>>(ns16, idx2, wt[4], B[4], wt[5], B[5], S16, Mw);
        update_mfma<<<NNODES / 32, 256, 0, stream>>>(ns, S16, Mw, wt[6], B[6], wt[7], B[7],
                                                     (float*)d_out);
    }
}

// Round 2
// 696.368 us; speedup vs baseline: 1.1412x; 1.1412x over previous
//
#include <hip/hip_runtime.h>
#include <cstdint>

#define HD 64
#define NNODES 200000
#define NS_ELEMS (NNODES * HD)          // 12,800,000

typedef short bf8 __attribute__((ext_vector_type(8)));
typedef short s2v __attribute__((ext_vector_type(2)));
typedef float f32x4 __attribute__((ext_vector_type(4)));

// ---- order-preserving float <-> uint for atomicMax ----
__device__ __forceinline__ unsigned enc_f32(float f) {
    unsigned u = __float_as_uint(f);
    return (u & 0x80000000u) ? ~u : (u | 0x80000000u);
}
__device__ __forceinline__ float dec_f32(unsigned v) {
    return (v & 0x80000000u) ? __uint_as_float(v & 0x7fffffffu)
                             : __uint_as_float(~v);
}

// RNE float -> bf16 bits, and back
__device__ __forceinline__ ushort f2bf(float f) {
    unsigned u = __float_as_uint(f);
    return (ushort)((u + 0x7fffu + ((u >> 16) & 1u)) >> 16);
}
__device__ __forceinline__ float bf2f(ushort b) {
    return __uint_as_float(((unsigned)b) << 16);
}

// ---- packed 2x bf16 atomic add (fallback path only) ----
__device__ __forceinline__ void atom_pk_add_bf16(ushort* p, ushort lo, ushort hi) {
    s2v v; v[0] = (short)lo; v[1] = (short)hi;
#if __has_builtin(__builtin_amdgcn_flat_atomic_fadd_v2bf16)
    (void)__builtin_amdgcn_flat_atomic_fadd_v2bf16((s2v*)p, v);
#elif __has_builtin(__builtin_amdgcn_global_atomic_fadd_v2bf16)
    (void)__builtin_amdgcn_global_atomic_fadd_v2bf16(
        (__attribute__((address_space(1))) s2v*)p, v);
#else
    unsigned* a = (unsigned*)p;
    unsigned old = *a, assumed;
    do {
        assumed = old;
        float f0 = bf2f((ushort)(assumed & 0xffffu)) + bf2f(lo);
        float f1 = bf2f((ushort)(assumed >> 16))     + bf2f(hi);
        unsigned nv = (unsigned)f2bf(f0) | ((unsigned)f2bf(f1) << 16);
        old = atomicCAS(a, assumed, nv);
    } while (old != assumed);
#endif
}

// ================= prep: ns fp32->bf16; weights fp32 -> bf16 frag-linear =====
struct PrepArgs {
    const float* src[8];
    ushort*      dst[8];
    int din[8], dout[8], nelem[8];
};

__global__ __launch_bounds__(256) void prep_kernel(
    const float* __restrict__ ns, ushort* __restrict__ ns16, PrepArgs pa, int total)
{
    int stride = gridDim.x * 256;
    for (int i = blockIdx.x * 256 + threadIdx.x; i < total; i += stride) {
        if (i < NS_ELEMS) { ns16[i] = f2bf(ns[i]); continue; }
        int e = i - NS_ELEMS;
        #pragma unroll
        for (int m = 0; m < 8; m++) {
            if (e < pa.nelem[m]) {
                int din = pa.din[m], dout = pa.dout[m];
                int n = e / din, k = e - n * din;
                pa.dst[m][(k >> 5) * dout * 32 + n * 32 + (k & 31)] = f2bf(pa.src[m][e]);
                e = 0x7fffffff;
            } else {
                e -= pa.nelem[m];
            }
        }
    }
}

// ================= CSR build: hist -> scan -> perm ==========================
__global__ __launch_bounds__(256) void hist_kernel(
    const int* __restrict__ i0, const int* __restrict__ i1, const int* __restrict__ i2,
    int b1e, int b2e, int total, int* __restrict__ cnt)
{
    int s = blockIdx.x * 256 + threadIdx.x;
    if (s >= total) return;
    int node = (s < b1e) ? i0[s] : (s < b2e ? i1[s - b1e] : i2[s - b2e]);
    atomicAdd(&cnt[node], 1);
}

__global__ __launch_bounds__(256) void scan1_kernel(
    const int* __restrict__ cnt, int* __restrict__ startv,
    int* __restrict__ partials, int n)
{
    __shared__ int wsum[4];
    int i = blockIdx.x * 256 + threadIdx.x;
    int v = (i < n) ? cnt[i] : 0;
    int lane = threadIdx.x & 63, wid = threadIdx.x >> 6;
    int x = v;
    #pragma unroll
    for (int off = 1; off < 64; off <<= 1) {
        int y = __shfl_up(x, off);
        if (lane >= off) x += y;
    }
    if (lane == 63) wsum[wid] = x;
    __syncthreads();
    int woff = 0;
    for (int w = 0; w < wid; w++) woff += wsum[w];
    int incl = x + woff;
    if (i < n) startv[i] = incl - v;              // block-local exclusive
    if (threadIdx.x == 255) partials[blockIdx.x] = incl;
}

__global__ __launch_bounds__(1024) void scan2_kernel(int* __restrict__ partials, int nb)
{
    __shared__ int sh[1024];
    int t = threadIdx.x;
    int orig = (t < nb) ? partials[t] : 0;
    sh[t] = orig;
    __syncthreads();
    for (int off = 1; off < 1024; off <<= 1) {
        int v = (t >= off) ? sh[t - off] : 0;
        __syncthreads();
        sh[t] += v;
        __syncthreads();
    }
    if (t < nb) partials[t] = sh[t] - orig;       // exclusive
}

__global__ __launch_bounds__(256) void scan3_kernel(
    int* __restrict__ startv, int* __restrict__ offv,
    const int* __restrict__ partials, int n, int total)
{
    int i = blockIdx.x * 256 + threadIdx.x;
    if (i < n) {
        int s = startv[i] + partials[blockIdx.x];
        startv[i] = s;
        offv[i] = s;
    }
    if (i == 0) startv[n] = total;
}

// perm[s] = destination row of slot s (linear write; atomic only on hot cursors)
__global__ __launch_bounds__(256) void fill_perm(
    const int* __restrict__ i0, const int* __restrict__ i1, const int* __restrict__ i2,
    int b1e, int b2e, int total, int* __restrict__ offv, int* __restrict__ perm)
{
    int s = blockIdx.x * 256 + threadIdx.x;
    if (s >= total) return;
    int node = (s < b1e) ? i0[s] : (s < b2e ? i1[s - b1e] : i2[s - b2e]);
    perm[s] = atomicAdd(&offv[node], 1);
}

// ================= one MFMA dense layer over a 32-row LDS tile ===============
template<int DIN, int DOUT, int NT, int PDIN>
__device__ __forceinline__ void mfma_layer(
    const ushort* __restrict__ WT, const float* __restrict__ bias,
    const ushort* __restrict__ Xs, int wave, int lane, f32x4 acc[2][NT])
{
    constexpr int KS = DIN / 32;
    const int q = lane >> 4, ln = lane & 15;
    const int n0 = wave * NT * 16;
    bf8 bf[NT][KS];
    #pragma unroll
    for (int nt = 0; nt < NT; nt++) {
        float bv = bias[n0 + nt * 16 + ln];
        acc[0][nt] = f32x4{bv, bv, bv, bv};
        acc[1][nt] = f32x4{bv, bv, bv, bv};
        #pragma unroll
        for (int ks = 0; ks < KS; ks++)
            bf[nt][ks] = *(const bf8*)(WT + (size_t)ks * DOUT * 32
                                          + (n0 + nt * 16 + ln) * 32 + q * 8);
    }
    #pragma unroll
    for (int mt = 0; mt < 2; mt++) {
        bf8 af[KS];
        #pragma unroll
        for (int ks = 0; ks < KS; ks++)
            af[ks] = *(const bf8*)(Xs + (mt * 16 + ln) * PDIN + ks * 32 + q * 8);
        #pragma unroll
        for (int ks = 0; ks < KS; ks++)
            #pragma unroll
            for (int nt = 0; nt < NT; nt++)
                acc[mt][nt] = __builtin_amdgcn_mfma_f32_16x16x32_bf16(
                    af[ks], bf[nt][ks], acc[mt][nt], 0, 0, 0);
    }
}

// ====== relation kernel: writes exp(8*o) rows to O2[perm[slot]] (full lines) =
template<int A>
__global__ __launch_bounds__(256) void rel_mfma_p(
    const ushort* __restrict__ ns16, const int* __restrict__ idx,
    const int* __restrict__ perm,
    const ushort* __restrict__ wt1, const float* __restrict__ b1,
    const ushort* __restrict__ wt2, const float* __restrict__ b2,
    ushort* __restrict__ O2, unsigned* __restrict__ Mword)
{
    constexpr int D  = A * HD;
    constexpr int PD = D + 8;
    constexpr int NT = D / 64;
    __shared__ __align__(16) ushort Xs[32 * PD];
    __shared__ __align__(16) ushort Hs[32 * PD];
    __shared__ int Pr[32 * A];
    __shared__ float wred[4];

    const int tid = threadIdx.x;
    const int t0  = blockIdx.x * 32;

    if (tid < 32 * A) Pr[tid] = perm[t0 * A + tid];
    for (int lin = tid; lin < 32 * A * 8; lin += 256) {
        int slot = lin >> 3, part = lin & 7;
        int node = idx[t0 * A + slot];
        int row = slot / A, sub = slot - row * A;
        *(uint4*)(Xs + row * PD + sub * 64 + part * 8) =
            *(const uint4*)(ns16 + (size_t)node * HD + part * 8);
    }
    __syncthreads();

    const int wave = tid >> 6, lane = tid & 63;
    const int q = lane >> 4, ln = lane & 15, n0 = wave * NT * 16;

    f32x4 acc[2][NT];
    mfma_layer<D, D, NT, PD>(wt1, b1, Xs, wave, lane, acc);
    #pragma unroll
    for (int mt = 0; mt < 2; mt++)
        #pragma unroll
        for (int nt = 0; nt < NT; nt++)
            #pragma unroll
            for (int r = 0; r < 4; r++)
                Hs[(mt * 16 + q * 4 + r) * PD + n0 + nt * 16 + ln] =
                    f2bf(fmaxf(acc[mt][nt][r], 0.f));
    __syncthreads();
    mfma_layer<D, D, NT, PD>(wt2, b2, Hs, wave, lane, acc);
    __syncthreads();                     // all waves done reading Hs

    // stage exp(8*o) in Hs (bf16), track block max
    float m = -3.0e38f;
    #pragma unroll
    for (int mt = 0; mt < 2; mt++)
        #pragma unroll
        for (int nt = 0; nt < NT; nt++) {
            int colg = n0 + nt * 16 + ln;
            #pragma unroll
            for (int r = 0; r < 4; r++) {
                float o = acc[mt][nt][r];
                m = fmaxf(m, o);
                Hs[(mt * 16 + q * 4 + r) * PD + colg] = f2bf(__expf(8.f * o));
            }
        }
    __syncthreads();

    // coalesced full-line row writes: 8 consecutive lanes x 16B per row
    for (int lin = tid; lin < 32 * A * 8; lin += 256) {
        int slot = lin >> 3, part = lin & 7;
        int trow = slot / A, sub = slot - trow * A;
        *(uint4*)(O2 + (size_t)Pr[slot] * HD + part * 8) =
            *(const uint4*)(Hs + trow * PD + sub * 64 + part * 8);
    }

    #pragma unroll
    for (int off = 32; off; off >>= 1) m = fmaxf(m, __shfl_xor(m, off));
    if (lane == 0) wred[wave] = m;
    __syncthreads();
    if (tid == 0)
        atomicMax(Mword, enc_f32(fmaxf(fmaxf(wred[0], wred[1]),
                                       fmaxf(wred[2], wred[3]))));
}

// ================= relation kernel: OLD (atomic scatter, fallback) ===========
template<int A>
__global__ __launch_bounds__(256) void rel_mfma(
    const ushort* __restrict__ ns16, const int* __restrict__ idx,
    const ushort* __restrict__ wt1, const float* __restrict__ b1,
    const ushort* __restrict__ wt2, const float* __restrict__ b2,
    ushort* __restrict__ S16, unsigned* __restrict__ Mword)
{
    constexpr int D  = A * HD;
    constexpr int PD = D + 8;
    constexpr int NT = D / 64;
    __shared__ __align__(16) ushort Xs[32 * PD];
    __shared__ __align__(16) ushort Hs[32 * PD];
    __shared__ int Is[32 * A];
    __shared__ float wred[4];

    const int tid = threadIdx.x;
    const int t0  = blockIdx.x * 32;

    if (tid < 32 * A) Is[tid] = idx[t0 * A + tid];
    for (int lin = tid; lin < 32 * A * 8; lin += 256) {
        int slot = lin >> 3, part = lin & 7;
        int node = idx[t0 * A + slot];
        int row = slot / A, sub = slot - row * A;
        *(uint4*)(Xs + row * PD + sub * 64 + part * 8) =
            *(const uint4*)(ns16 + (size_t)node * HD + part * 8);
    }
    __syncthreads();

    const int wave = tid >> 6, lane = tid & 63;
    const int q = lane >> 4, ln = lane & 15, n0 = wave * NT * 16;

    f32x4 acc[2][NT];
    mfma_layer<D, D, NT, PD>(wt1, b1, Xs, wave, lane, acc);
    #pragma unroll
    for (int mt = 0; mt < 2; mt++)
        #pragma unroll
        for (int nt = 0; nt < NT; nt++)
            #pragma unroll
            for (int r = 0; r < 4; r++)
                Hs[(mt * 16 + q * 4 + r) * PD + n0 + nt * 16 + ln] =
                    f2bf(fmaxf(acc[mt][nt][r], 0.f));
    __syncthreads();
    mfma_layer<D, D, NT, PD>(wt2, b2, Hs, wave, lane, acc);

    float m = -3.0e38f;
    const bool even = (ln & 1) == 0;
    #pragma unroll
    for (int mt = 0; mt < 2; mt++)
        #pragma unroll
        for (int nt = 0; nt < NT; nt++) {
            int colg = n0 + nt * 16 + ln;
            int sub  = colg >> 6;
            int featp = (colg & 63) & ~1;
            float e[4], p[4];
            #pragma unroll
            for (int r = 0; r < 4; r++) {
                float o = acc[mt][nt][r];
                m = fmaxf(m, o);
                e[r] = __expf(8.f * o);
            }
            #pragma unroll
            for (int r = 0; r < 4; r++) p[r] = __shfl_xor(e[r], 1);
            #pragma unroll
            for (int j = 0; j < 2; j++) {
                int r   = even ? j : (2 + j);
                int row = mt * 16 + q * 4 + r;
                int node = Is[row * A + sub];
                ushort lo = even ? f2bf(e[r]) : f2bf(p[r]);
                ushort hi = even ? f2bf(p[r]) : f2bf(e[r]);
                atom_pk_add_bf16(S16 + (size_t)node * HD + featp, lo, hi);
            }
        }
    #pragma unroll
    for (int off = 32; off; off >>= 1) m = fmaxf(m, __shfl_xor(m, off));
    if (lane == 0) wred[wave] = m;
    __syncthreads();
    if (tid == 0)
        atomicMax(Mword, enc_f32(fmaxf(fmaxf(wred[0], wred[1]),
                                       fmaxf(wred[2], wred[3]))));
}

// ===== update kernel: contiguous segment reduce (streaming) + MFMA ==========
__global__ __launch_bounds__(256) void update_lin(
    const float* __restrict__ ns, const ushort* __restrict__ O2,
    const int* __restrict__ startv,
    const unsigned* __restrict__ Mword,
    const ushort* __restrict__ wt1, const float* __restrict__ b1,
    const ushort* __restrict__ wt2, const float* __restrict__ b2,
    float* __restrict__ out)
{
    constexpr int D = 128, PD = D + 8;
    __shared__ __align__(16) ushort Xs[32 * PD];
    __shared__ __align__(16) ushort Hs[32 * PD];

    const int tid = threadIdx.x;
    const int r0  = blockIdx.x * 32;
    const float corr = 1e-16f * __expf(8.f * dec_f32(*Mword));

    // ns half: rows 0..31, cols 64..127
    for (int lin = tid; lin < 32 * 8; lin += 256) {
        int row = lin >> 3, p8 = (lin & 7) * 8;
        const float* src = ns + (size_t)(r0 + row) * HD + p8;
        float4 a = *(const float4*)src;
        float4 b = *(const float4*)(src + 4);
        ushort tmp[8] = { f2bf(a.x), f2bf(a.y), f2bf(a.z), f2bf(a.w),
                          f2bf(b.x), f2bf(b.y), f2bf(b.z), f2bf(b.w) };
        *(uint4*)(Xs + row * PD + 64 + p8) = *(uint4*)tmp;
    }

    // segmented reduce over CONTIGUOUS rows: thread t owns (node tid>>3, feats (tid&7)*8)
    {
        const int row = tid >> 3, f0 = (tid & 7) * 8;
        const int s0 = startv[r0 + row];
        const int s1 = startv[r0 + row + 1];
        float sum[8] = {0.f, 0.f, 0.f, 0.f, 0.f, 0.f, 0.f, 0.f};
        int k = s0;
        for (; k + 1 < s1; k += 2) {
            ushort ra[8], rb[8];
            *(uint4*)ra = *(const uint4*)(O2 + (size_t)k * HD + f0);
            *(uint4*)rb = *(const uint4*)(O2 + (size_t)(k + 1) * HD + f0);
            #pragma unroll
            for (int j = 0; j < 8; j++) sum[j] += bf2f(ra[j]) + bf2f(rb[j]);
        }
        if (k < s1) {
            ushort ra[8];
            *(uint4*)ra = *(const uint4*)(O2 + (size_t)k * HD + f0);
            #pragma unroll
            for (int j = 0; j < 8; j++) sum[j] += bf2f(ra[j]);
        }
        ushort tmp[8];
        #pragma unroll
        for (int j = 0; j < 8; j++)
            tmp[j] = f2bf(0.125f * __logf(sum[j] + corr));
        *(uint4*)(Xs + row * PD + f0) = *(uint4*)tmp;
    }
    __syncthreads();

    const int wave = tid >> 6, lane = tid & 63;
    const int q = lane >> 4, ln = lane & 15;

    f32x4 acc[2][2];
    mfma_layer<128, 128, 2, PD>(wt1, b1, Xs, wave, lane, acc);
    #pragma unroll
    for (int mt = 0; mt < 2; mt++)
        #pragma unroll
        for (int nt = 0; nt < 2; nt++)
            #pragma unroll
            for (int r = 0; r < 4; r++)
                Hs[(mt * 16 + q * 4 + r) * PD + wave * 32 + nt * 16 + ln] =
                    f2bf(fmaxf(acc[mt][nt][r], 0.f));
    __syncthreads();

    f32x4 acc2[2][1];
    mfma_layer<128, 64, 1, PD>(wt2, b2, Hs, wave, lane, acc2);
    #pragma unroll
    for (int mt = 0; mt < 2; mt++)
        #pragma unroll
        for (int r = 0; r < 4; r++)
            out[(size_t)(r0 + mt * 16 + q * 4 + r) * HD + wave * 16 + ln] =
                acc2[mt][0][r];
}

// ================= update kernel: OLD (bf16-accum read, fallback) ============
__global__ __launch_bounds__(256) void update_mfma(
    const float* __restrict__ ns, const ushort* __restrict__ S16,
    const unsigned* __restrict__ Mword,
    const ushort* __restrict__ wt1, const float* __restrict__ b1,
    const ushort* __restrict__ wt2, const float* __restrict__ b2,
    float* __restrict__ out)
{
    constexpr int D = 128, PD = D + 8;
    __shared__ __align__(16) ushort Xs[32 * PD];
    __shared__ __align__(16) ushort Hs[32 * PD];

    const int tid = threadIdx.x;
    const int r0  = blockIdx.x * 32;
    const float corr = 1e-16f * __expf(8.f * dec_f32(*Mword));

    for (int lin = tid; lin < 32 * 16; lin += 256) {
        int row = lin >> 4, c8 = (lin & 15) * 8;
        ushort tmp[8];
        if (c8 < 64) {
            ushort raw[8];
            *(uint4*)raw = *(const uint4*)(S16 + (size_t)(r0 + row) * HD + c8);
            #pragma unroll
            for (int j = 0; j < 8; j++)
                tmp[j] = f2bf(0.125f * __logf(bf2f(raw[j]) + corr));
        } else {
            #pragma unroll
            for (int j = 0; j < 8; j++)
                tmp[j] = f2bf(ns[(size_t)(r0 + row) * HD + (c8 - 64) + j]);
        }
        *(uint4*)(Xs + row * PD + c8) = *(uint4*)tmp;
    }
    __syncthreads();

    const int wave = tid >> 6, lane = tid & 63;
    const int q = lane >> 4, ln = lane & 15;

    f32x4 acc[2][2];
    mfma_layer<128, 128, 2, PD>(wt1, b1, Xs, wave, lane, acc);
    #pragma unroll
    for (int mt = 0; mt < 2; mt++)
        #pragma unroll
        for (int nt = 0; nt < 2; nt++)
            #pragma unroll
            for (int r = 0; r < 4; r++)
                Hs[(mt * 16 + q * 4 + r) * PD + wave * 32 + nt * 16 + ln] =
                    f2bf(fmaxf(acc[mt][nt][r], 0.f));
    __syncthreads();

    f32x4 acc2[2][1];
    mfma_layer<128, 64, 1, PD>(wt2, b2, Hs, wave, lane, acc2);
    #pragma unroll
    for (int mt = 0; mt < 2; mt++)
        #pragma unroll
        for (int r = 0; r < 4; r++)
            out[(size_t)(r0 + mt * 16 + q * 4 + r) * HD + wave * 16 + ln] =
                acc2[mt][0][r];
}

// ================= host =====================================================
extern "C" void kernel_launch(void* const* d_in, const int* in_sizes, int n_in,
                              void* d_out, int out_size, void* d_ws, size_t ws_size,
                              hipStream_t stream)
{
    const float* ns   = (const float*)d_in[0];
    const int*   idx0 = (const int*)d_in[1];
    const int*   idx1 = (const int*)d_in[2];
    const int*   idx2 = (const int*)d_in[3];
    const float* W[8] = { (const float*)d_in[4],  (const float*)d_in[6],
                          (const float*)d_in[8],  (const float*)d_in[10],
                          (const float*)d_in[12], (const float*)d_in[14],
                          (const float*)d_in[16], (const float*)d_in[18] };
    const float* B[8] = { (const float*)d_in[5],  (const float*)d_in[7],
                          (const float*)d_in[9],  (const float*)d_in[11],
                          (const float*)d_in[13], (const float*)d_in[15],
                          (const float*)d_in[17], (const float*)d_in[19] };
    static const int DIN[8]  = {128,128,128,128,192,192,128,128};
    static const int DOUT[8] = {128,128,128,128,192,192,128, 64};

    const int n0f = in_sizes[1];          // 600000 flat ints
    const int n1f = in_sizes[2];          // 600000
    const int n2f = in_sizes[3];          // 600000
    const int TOT = n0f + n1f + n2f;      // 1,800,000
    const int T0 = n0f / 2, T1 = n1f / 2, T2 = n2f / 3;

    size_t wtot = 0;
    for (int m = 0; m < 8; m++) wtot += (size_t)DIN[m] * DOUT[m];   // 360,448

    // ---- new-path workspace layout ----
    size_t oO     = 0;
    size_t oNs    = oO  + (size_t)TOT * HD * 2;                     // O2: 230.4 MB
    size_t oWT    = oNs + (size_t)NS_ELEMS * 2;                     // ns16: 25.6 MB
    size_t oPerm  = oWT + ((wtot * 2 + 255) & ~(size_t)255);
    size_t oStart = oPerm + (((size_t)TOT * 4 + 255) & ~(size_t)255);
    size_t oOff   = oStart + (((size_t)(NNODES + 1) * 4 + 255) & ~(size_t)255);
    size_t oPart  = oOff + (size_t)NNODES * 4;
    size_t oCnt   = oPart + 4096;
    size_t oMw    = oCnt + (size_t)NNODES * 4;
    size_t NEED   = oMw + 64;

    if (ws_size >= NEED) {
        // ================= perm / streaming path =================
        ushort*   O2    = (ushort*)d_ws;
        ushort*   ns16  = (ushort*)((char*)d_ws + oNs);
        ushort*   WTb   = (ushort*)((char*)d_ws + oWT);
        int*      perm  = (int*)((char*)d_ws + oPerm);
        int*      start = (int*)((char*)d_ws + oStart);
        int*      offp  = (int*)((char*)d_ws + oOff);
        int*      part  = (int*)((char*)d_ws + oPart);
        int*      cnt   = (int*)((char*)d_ws + oCnt);
        unsigned* Mw    = (unsigned*)((char*)d_ws + oMw);

        PrepArgs pa;
        int total = NS_ELEMS;
        ushort* wt[8];
        {
            ushort* p = WTb;
            for (int m = 0; m < 8; m++) {
                pa.src[m] = W[m];
                pa.dst[m] = p;  wt[m] = p;
                pa.din[m] = DIN[m]; pa.dout[m] = DOUT[m];
                pa.nelem[m] = DIN[m] * DOUT[m];
                p += pa.nelem[m];
                total += pa.nelem[m];
            }
        }

        hipMemsetAsync((char*)d_ws + oCnt, 0, (size_t)NNODES * 4 + 64, stream);
        prep_kernel<<<4096, 256, 0, stream>>>(ns, ns16, pa, total);

        const int NB   = (NNODES + 255) / 256;
        const int gTOT = (TOT + 255) / 256;
        hist_kernel<<<gTOT, 256, 0, stream>>>(idx0, idx1, idx2, n0f, n0f + n1f, TOT, cnt);
        scan1_kernel<<<NB, 256, 0, stream>>>(cnt, start, part, NNODES);
        scan2_kernel<<<1, 1024, 0, stream>>>(part, NB);
        scan3_kernel<<<NB, 256, 0, stream>>>(start, offp, part, NNODES, TOT);
        fill_perm<<<gTOT, 256, 0, stream>>>(idx0, idx1, idx2, n0f, n0f + n1f, TOT, offp, perm);

        rel_mfma_p<2><<<T0 / 32, 256, 0, stream>>>(
            ns16, idx0, perm, wt[0], B[0], wt[1], B[1], O2, Mw);
        rel_mfma_p<2><<<T1 / 32, 256, 0, stream>>>(
            ns16, idx1, perm + n0f, wt[2], B[2], wt[3], B[3], O2, Mw);
        rel_mfma_p<3><<<T2 / 32, 256, 0, stream>>>(
            ns16, idx2, perm + n0f + n1f, wt[4], B[4], wt[5], B[5], O2, Mw);

        update_lin<<<NNODES / 32, 256, 0, stream>>>(
            ns, O2, start, Mw, wt[6], B[6], wt[7], B[7], (float*)d_out);
    } else {
        // ================= fallback: previous atomic path =================
        ushort*   S16  = (ushort*)d_ws;
        size_t    offM = (size_t)NNODES * HD * sizeof(ushort);
        unsigned* Mw   = (unsigned*)((char*)d_ws + offM);
        ushort*   ns16 = (ushort*)((char*)d_ws + offM + 64);
        ushort*   WTb  = ns16 + (size_t)NS_ELEMS;

        PrepArgs pa;
        int total = NS_ELEMS;
        ushort* wt[8];
        {
            ushort* p = WTb;
            for (int m = 0; m < 8; m++) {
                pa.src[m] = W[m];
                pa.dst[m] = p;  wt[m] = p;
                pa.din[m] = DIN[m]; pa.dout[m] = DOUT[m];
                pa.nelem[m] = DIN[m] * DOUT[m];
                p += pa.nelem[m];
                total += pa.nelem[m];
            }
        }

        hipMemsetAsync(d_ws, 0, offM + 64, stream);
        prep_kernel<<<4096, 256, 0, stream>>>(ns, ns16, pa, total);

        rel_mfma<2><<<T0 / 32, 256, 0, stream>>>(ns16, idx0, wt[0], B[0], wt[1], B[1], S16, Mw);
        rel_mfma<2><<<T1 / 32, 256, 0, stream>>>(ns16, idx1, wt[2], B[2], wt[3], B[3], S16, Mw);
        rel_mfma<3><<<T2 / 32, 256, 0, stream>>>(ns16, idx2, wt[4], B[4], wt[5], B[5], S16, Mw);
        update_mfma<<<NNODES / 32, 256, 0, stream>>>(ns, S16, Mw, wt[6], B[6], wt[7], B[7],
                                                     (float*)d_out);
    }
}

// Round 3
// 576.296 us; speedup vs baseline: 1.3790x; 1.2084x over previous
//
#include <hip/hip_runtime.h>
#include <cstdint>

#define HD 64
#define NNODES 200000
#define NS_ELEMS (NNODES * HD)          // 12,800,000

typedef short bf8 __attribute__((ext_vector_type(8)));
typedef short s2v __attribute__((ext_vector_type(2)));
typedef float f32x4 __attribute__((ext_vector_type(4)));

// ---- order-preserving float <-> uint for atomicMax ----
__device__ __forceinline__ unsigned enc_f32(float f) {
    unsigned u = __float_as_uint(f);
    return (u & 0x80000000u) ? ~u : (u | 0x80000000u);
}
__device__ __forceinline__ float dec_f32(unsigned v) {
    return (v & 0x80000000u) ? __uint_as_float(v & 0x7fffffffu)
                             : __uint_as_float(~v);
}

// RNE float -> bf16 bits, and back
__device__ __forceinline__ ushort f2bf(float f) {
    unsigned u = __float_as_uint(f);
    return (ushort)((u + 0x7fffu + ((u >> 16) & 1u)) >> 16);
}
__device__ __forceinline__ float bf2f(ushort b) {
    return __uint_as_float(((unsigned)b) << 16);
}

// ---- packed 2x bf16 atomic add (fallback path only) ----
__device__ __forceinline__ void atom_pk_add_bf16(ushort* p, ushort lo, ushort hi) {
    s2v v; v[0] = (short)lo; v[1] = (short)hi;
#if __has_builtin(__builtin_amdgcn_flat_atomic_fadd_v2bf16)
    (void)__builtin_amdgcn_flat_atomic_fadd_v2bf16((s2v*)p, v);
#elif __has_builtin(__builtin_amdgcn_global_atomic_fadd_v2bf16)
    (void)__builtin_amdgcn_global_atomic_fadd_v2bf16(
        (__attribute__((address_space(1))) s2v*)p, v);
#else
    unsigned* a = (unsigned*)p;
    unsigned old = *a, assumed;
    do {
        assumed = old;
        float f0 = bf2f((ushort)(assumed & 0xffffu)) + bf2f(lo);
        float f1 = bf2f((ushort)(assumed >> 16))     + bf2f(hi);
        unsigned nv = (unsigned)f2bf(f0) | ((unsigned)f2bf(f1) << 16);
        old = atomicCAS(a, assumed, nv);
    } while (old != assumed);
#endif
}

// ================= prep: ns fp32->bf16; weights fp32 -> bf16 frag-linear =====
struct PrepArgs {
    const float* src[8];
    ushort*      dst[8];
    int din[8], dout[8], nelem[8];
};

__global__ __launch_bounds__(256) void prep_kernel(
    const float* __restrict__ ns, ushort* __restrict__ ns16, PrepArgs pa, int total)
{
    int stride = gridDim.x * 256;
    for (int i = blockIdx.x * 256 + threadIdx.x; i < total; i += stride) {
        if (i < NS_ELEMS) { ns16[i] = f2bf(ns[i]); continue; }
        int e = i - NS_ELEMS;
        #pragma unroll
        for (int m = 0; m < 8; m++) {
            if (e < pa.nelem[m]) {
                int din = pa.din[m], dout = pa.dout[m];
                int n = e / din, k = e - n * din;
                pa.dst[m][(k >> 5) * dout * 32 + n * 32 + (k & 31)] = f2bf(pa.src[m][e]);
                e = 0x7fffffff;
            } else {
                e -= pa.nelem[m];
            }
        }
    }
}

// ================= CSR build: hist -> scan -> perm ==========================
__global__ __launch_bounds__(256) void hist_kernel(
    const int* __restrict__ i0, const int* __restrict__ i1, const int* __restrict__ i2,
    int b1e, int b2e, int total, int* __restrict__ cnt)
{
    int s = blockIdx.x * 256 + threadIdx.x;
    if (s >= total) return;
    int node = (s < b1e) ? i0[s] : (s < b2e ? i1[s - b1e] : i2[s - b2e]);
    atomicAdd(&cnt[node], 1);
}

__global__ __launch_bounds__(256) void scan1_kernel(
    const int* __restrict__ cnt, int* __restrict__ startv,
    int* __restrict__ partials, int n)
{
    __shared__ int wsum[4];
    int i = blockIdx.x * 256 + threadIdx.x;
    int v = (i < n) ? cnt[i] : 0;
    int lane = threadIdx.x & 63, wid = threadIdx.x >> 6;
    int x = v;
    #pragma unroll
    for (int off = 1; off < 64; off <<= 1) {
        int y = __shfl_up(x, off);
        if (lane >= off) x += y;
    }
    if (lane == 63) wsum[wid] = x;
    __syncthreads();
    int woff = 0;
    for (int w = 0; w < wid; w++) woff += wsum[w];
    int incl = x + woff;
    if (i < n) startv[i] = incl - v;              // block-local exclusive
    if (threadIdx.x == 255) partials[blockIdx.x] = incl;
}

__global__ __launch_bounds__(1024) void scan2_kernel(int* __restrict__ partials, int nb)
{
    __shared__ int sh[1024];
    int t = threadIdx.x;
    int orig = (t < nb) ? partials[t] : 0;
    sh[t] = orig;
    __syncthreads();
    for (int off = 1; off < 1024; off <<= 1) {
        int v = (t >= off) ? sh[t - off] : 0;
        __syncthreads();
        sh[t] += v;
        __syncthreads();
    }
    if (t < nb) partials[t] = sh[t] - orig;       // exclusive
}

__global__ __launch_bounds__(256) void scan3_kernel(
    int* __restrict__ startv, int* __restrict__ offv,
    const int* __restrict__ partials, int n, int total)
{
    int i = blockIdx.x * 256 + threadIdx.x;
    if (i < n) {
        int s = startv[i] + partials[blockIdx.x];
        startv[i] = s;
        offv[i] = s;
    }
    if (i == 0) startv[n] = total;
}

// perm[s] = destination row of slot s (linear write; atomic only on hot cursors)
__global__ __launch_bounds__(256) void fill_perm(
    const int* __restrict__ i0, const int* __restrict__ i1, const int* __restrict__ i2,
    int b1e, int b2e, int total, int* __restrict__ offv, int* __restrict__ perm)
{
    int s = blockIdx.x * 256 + threadIdx.x;
    if (s >= total) return;
    int node = (s < b1e) ? i0[s] : (s < b2e ? i1[s - b1e] : i2[s - b2e]);
    perm[s] = atomicAdd(&offv[node], 1);
}

// ================= one MFMA dense layer over a 32-row LDS tile ===============
template<int DIN, int DOUT, int NT, int PDIN>
__device__ __forceinline__ void mfma_layer(
    const ushort* __restrict__ WT, const float* __restrict__ bias,
    const ushort* __restrict__ Xs, int wave, int lane, f32x4 acc[2][NT])
{
    constexpr int KS = DIN / 32;
    const int q = lane >> 4, ln = lane & 15;
    const int n0 = wave * NT * 16;
    bf8 bf[NT][KS];
    #pragma unroll
    for (int nt = 0; nt < NT; nt++) {
        float bv = bias[n0 + nt * 16 + ln];
        acc[0][nt] = f32x4{bv, bv, bv, bv};
        acc[1][nt] = f32x4{bv, bv, bv, bv};
        #pragma unroll
        for (int ks = 0; ks < KS; ks++)
            bf[nt][ks] = *(const bf8*)(WT + (size_t)ks * DOUT * 32
                                          + (n0 + nt * 16 + ln) * 32 + q * 8);
    }
    #pragma unroll
    for (int mt = 0; mt < 2; mt++) {
        bf8 af[KS];
        #pragma unroll
        for (int ks = 0; ks < KS; ks++)
            af[ks] = *(const bf8*)(Xs + (mt * 16 + ln) * PDIN + ks * 32 + q * 8);
        #pragma unroll
        for (int ks = 0; ks < KS; ks++)
            #pragma unroll
            for (int nt = 0; nt < NT; nt++)
                acc[mt][nt] = __builtin_amdgcn_mfma_f32_16x16x32_bf16(
                    af[ks], bf[nt][ks], acc[mt][nt], 0, 0, 0);
    }
}

// ====== relation kernel: persistent, pipelined, perm-scatter writes =========
template<int A>
__global__ __launch_bounds__(256) void rel_mfma_pp(
    const ushort* __restrict__ ns16, const int* __restrict__ idx,
    const int* __restrict__ perm,
    const ushort* __restrict__ wt1, const float* __restrict__ b1,
    const ushort* __restrict__ wt2, const float* __restrict__ b2,
    ushort* __restrict__ O2, unsigned* __restrict__ Mword, int ntiles)
{
    constexpr int D  = A * HD;
    constexpr int PD = D + 8;
    constexpr int NT = D / 64;
    __shared__ __align__(16) ushort Xs[2][32 * PD];
    __shared__ __align__(16) ushort Hs[32 * PD];
    __shared__ int Pr[2][32 * A];
    __shared__ float wred[4];

    const int tid  = threadIdx.x;
    const int wave = tid >> 6, lane = tid & 63;
    const int q = lane >> 4, ln = lane & 15, n0 = wave * NT * 16;

    uint4 greg[A];
    int   pv = 0;
    float mblk = -3.0e38f;

    int ti = blockIdx.x;
    if (ti < ntiles) {
        // prologue gather: tile ti -> Xs[0]
        int t0 = ti * 32;
        #pragma unroll
        for (int k = 0; k < A; k++) {
            int j = tid + k * 256;
            int slot = j >> 3, part = j & 7;
            int node = idx[t0 * A + slot];
            greg[k] = *(const uint4*)(ns16 + (size_t)node * HD + part * 8);
        }
        if (tid < 32 * A) pv = perm[t0 * A + tid];
        #pragma unroll
        for (int k = 0; k < A; k++) {
            int j = tid + k * 256;
            int slot = j >> 3, part = j & 7;
            int row = slot / A, sub = slot - row * A;
            *(uint4*)(&Xs[0][row * PD + sub * 64 + part * 8]) = greg[k];
        }
        if (tid < 32 * A) Pr[0][tid] = pv;
        __syncthreads();

        int cur = 0;
        for (;;) {
            int tn = ti + gridDim.x;
            bool has_next = tn < ntiles;
            if (has_next) {
                // issue next tile's gather early (hidden under compute)
                int t0n = tn * 32;
                #pragma unroll
                for (int k = 0; k < A; k++) {
                    int j = tid + k * 256;
                    int slot = j >> 3, part = j & 7;
                    int node = idx[t0n * A + slot];
                    greg[k] = *(const uint4*)(ns16 + (size_t)node * HD + part * 8);
                }
                if (tid < 32 * A) pv = perm[t0n * A + tid];
            }

            // ---- compute current tile from Xs[cur]
            f32x4 acc[2][NT];
            mfma_layer<D, D, NT, PD>(wt1, b1, Xs[cur], wave, lane, acc);
            #pragma unroll
            for (int mt = 0; mt < 2; mt++)
                #pragma unroll
                for (int nt = 0; nt < NT; nt++)
                    #pragma unroll
                    for (int r = 0; r < 4; r++)
                        Hs[(mt * 16 + q * 4 + r) * PD + n0 + nt * 16 + ln] =
                            f2bf(fmaxf(acc[mt][nt][r], 0.f));
            __syncthreads();                       // (1) Hs ready for layer2
            mfma_layer<D, D, NT, PD>(wt2, b2, Hs, wave, lane, acc);
            __syncthreads();                       // (2) Hs reads done

            // exp staging into Hs, block-max tracking
            #pragma unroll
            for (int mt = 0; mt < 2; mt++)
                #pragma unroll
                for (int nt = 0; nt < NT; nt++) {
                    int colg = n0 + nt * 16 + ln;
                    #pragma unroll
                    for (int r = 0; r < 4; r++) {
                        float o = acc[mt][nt][r];
                        mblk = fmaxf(mblk, o);
                        Hs[(mt * 16 + q * 4 + r) * PD + colg] = f2bf(__expf(8.f * o));
                    }
                }
            __syncthreads();                       // (3) exp rows ready

            // coalesced full-line scatter: row -> O2[Pr[slot]]
            #pragma unroll
            for (int k = 0; k < A; k++) {
                int j = tid + k * 256;
                int slot = j >> 3, part = j & 7;
                int row = slot / A, sub = slot - row * A;
                *(uint4*)(O2 + (size_t)Pr[cur][slot] * HD + part * 8) =
                    *(const uint4*)(&Hs[row * PD + sub * 64 + part * 8]);
            }

            if (!has_next) break;

            __syncthreads();                       // (4) Hs scatter-reads done
            int nxt = cur ^ 1;
            #pragma unroll
            for (int k = 0; k < A; k++) {
                int j = tid + k * 256;
                int slot = j >> 3, part = j & 7;
                int row = slot / A, sub = slot - row * A;
                *(uint4*)(&Xs[nxt][row * PD + sub * 64 + part * 8]) = greg[k];
            }
            if (tid < 32 * A) Pr[nxt][tid] = pv;
            __syncthreads();                       // (5) Xs[nxt]/Pr[nxt] ready
            cur = nxt;
            ti = tn;
        }
    }

    // block max -> single atomic per persistent block
    #pragma unroll
    for (int off = 32; off; off >>= 1) mblk = fmaxf(mblk, __shfl_xor(mblk, off));
    if (lane == 0) wred[wave] = mblk;
    __syncthreads();
    if (tid == 0)
        atomicMax(Mword, enc_f32(fmaxf(fmaxf(wred[0], wred[1]),
                                       fmaxf(wred[2], wred[3]))));
}

// ================= relation kernel: OLD (atomic scatter, fallback) ===========
template<int A>
__global__ __launch_bounds__(256) void rel_mfma(
    const ushort* __restrict__ ns16, const int* __restrict__ idx,
    const ushort* __restrict__ wt1, const float* __restrict__ b1,
    const ushort* __restrict__ wt2, const float* __restrict__ b2,
    ushort* __restrict__ S16, unsigned* __restrict__ Mword)
{
    constexpr int D  = A * HD;
    constexpr int PD = D + 8;
    constexpr int NT = D / 64;
    __shared__ __align__(16) ushort Xs[32 * PD];
    __shared__ __align__(16) ushort Hs[32 * PD];
    __shared__ int Is[32 * A];
    __shared__ float wred[4];

    const int tid = threadIdx.x;
    const int t0  = blockIdx.x * 32;

    if (tid < 32 * A) Is[tid] = idx[t0 * A + tid];
    for (int lin = tid; lin < 32 * A * 8; lin += 256) {
        int slot = lin >> 3, part = lin & 7;
        int node = idx[t0 * A + slot];
        int row = slot / A, sub = slot - row * A;
        *(uint4*)(Xs + row * PD + sub * 64 + part * 8) =
            *(const uint4*)(ns16 + (size_t)node * HD + part * 8);
    }
    __syncthreads();

    const int wave = tid >> 6, lane = tid & 63;
    const int q = lane >> 4, ln = lane & 15, n0 = wave * NT * 16;

    f32x4 acc[2][NT];
    mfma_layer<D, D, NT, PD>(wt1, b1, Xs, wave, lane, acc);
    #pragma unroll
    for (int mt = 0; mt < 2; mt++)
        #pragma unroll
        for (int nt = 0; nt < NT; nt++)
            #pragma unroll
            for (int r = 0; r < 4; r++)
                Hs[(mt * 16 + q * 4 + r) * PD + n0 + nt * 16 + ln] =
                    f2bf(fmaxf(acc[mt][nt][r], 0.f));
    __syncthreads();
    mfma_layer<D, D, NT, PD>(wt2, b2, Hs, wave, lane, acc);

    float m = -3.0e38f;
    const bool even = (ln & 1) == 0;
    #pragma unroll
    for (int mt = 0; mt < 2; mt++)
        #pragma unroll
        for (int nt = 0; nt < NT; nt++) {
            int colg = n0 + nt * 16 + ln;
            int sub  = colg >> 6;
            int featp = (colg & 63) & ~1;
            float e[4], p[4];
            #pragma unroll
            for (int r = 0; r < 4; r++) {
                float o = acc[mt][nt][r];
                m = fmaxf(m, o);
                e[r] = __expf(8.f * o);
            }
            #pragma unroll
            for (int r = 0; r < 4; r++) p[r] = __shfl_xor(e[r], 1);
            #pragma unroll
            for (int j = 0; j < 2; j++) {
                int r   = even ? j : (2 + j);
                int row = mt * 16 + q * 4 + r;
                int node = Is[row * A + sub];
                ushort lo = even ? f2bf(e[r]) : f2bf(p[r]);
                ushort hi = even ? f2bf(p[r]) : f2bf(e[r]);
                atom_pk_add_bf16(S16 + (size_t)node * HD + featp, lo, hi);
            }
        }
    #pragma unroll
    for (int off = 32; off; off >>= 1) m = fmaxf(m, __shfl_xor(m, off));
    if (lane == 0) wred[wave] = m;
    __syncthreads();
    if (tid == 0)
        atomicMax(Mword, enc_f32(fmaxf(fmaxf(wred[0], wred[1]),
                                       fmaxf(wred[2], wred[3]))));
}

// ===== update kernel: contiguous segment reduce (streaming) + MFMA ==========
__global__ __launch_bounds__(256) void update_lin(
    const float* __restrict__ ns, const ushort* __restrict__ O2,
    const int* __restrict__ startv,
    const unsigned* __restrict__ Mword,
    const ushort* __restrict__ wt1, const float* __restrict__ b1,
    const ushort* __restrict__ wt2, const float* __restrict__ b2,
    float* __restrict__ out)
{
    constexpr int D = 128, PD = D + 8;
    __shared__ __align__(16) ushort Xs[32 * PD];
    __shared__ __align__(16) ushort Hs[32 * PD];

    const int tid = threadIdx.x;
    const int r0  = blockIdx.x * 32;
    const float corr = 1e-16f * __expf(8.f * dec_f32(*Mword));

    // ns half: rows 0..31, cols 64..127
    for (int lin = tid; lin < 32 * 8; lin += 256) {
        int row = lin >> 3, p8 = (lin & 7) * 8;
        const float* src = ns + (size_t)(r0 + row) * HD + p8;
        float4 a = *(const float4*)src;
        float4 b = *(const float4*)(src + 4);
        ushort tmp[8] = { f2bf(a.x), f2bf(a.y), f2bf(a.z), f2bf(a.w),
                          f2bf(b.x), f2bf(b.y), f2bf(b.z), f2bf(b.w) };
        *(uint4*)(Xs + row * PD + 64 + p8) = *(uint4*)tmp;
    }

    // segmented reduce over CONTIGUOUS rows: thread t owns (node tid>>3, feats (tid&7)*8)
    {
        const int row = tid >> 3, f0 = (tid & 7) * 8;
        const int s0 = startv[r0 + row];
        const int s1 = startv[r0 + row + 1];
        float sum[8] = {0.f, 0.f, 0.f, 0.f, 0.f, 0.f, 0.f, 0.f};
        int k = s0;
        for (; k + 1 < s1; k += 2) {
            ushort ra[8], rb[8];
            *(uint4*)ra = *(const uint4*)(O2 + (size_t)k * HD + f0);
            *(uint4*)rb = *(const uint4*)(O2 + (size_t)(k + 1) * HD + f0);
            #pragma unroll
            for (int j = 0; j < 8; j++) sum[j] += bf2f(ra[j]) + bf2f(rb[j]);
        }
        if (k < s1) {
            ushort ra[8];
            *(uint4*)ra = *(const uint4*)(O2 + (size_t)k * HD + f0);
            #pragma unroll
            for (int j = 0; j < 8; j++) sum[j] += bf2f(ra[j]);
        }
        ushort tmp[8];
        #pragma unroll
        for (int j = 0; j < 8; j++)
            tmp[j] = f2bf(0.125f * __logf(sum[j] + corr));
        *(uint4*)(Xs + row * PD + f0) = *(uint4*)tmp;
    }
    __syncthreads();

    const int wave = tid >> 6, lane = tid & 63;
    const int q = lane >> 4, ln = lane & 15;

    f32x4 acc[2][2];
    mfma_layer<128, 128, 2, PD>(wt1, b1, Xs, wave, lane, acc);
    #pragma unroll
    for (int mt = 0; mt < 2; mt++)
        #pragma unroll
        for (int nt = 0; nt < 2; nt++)
            #pragma unroll
            for (int r = 0; r < 4; r++)
                Hs[(mt * 16 + q * 4 + r) * PD + wave * 32 + nt * 16 + ln] =
                    f2bf(fmaxf(acc[mt][nt][r], 0.f));
    __syncthreads();

    f32x4 acc2[2][1];
    mfma_layer<128, 64, 1, PD>(wt2, b2, Hs, wave, lane, acc2);
    #pragma unroll
    for (int mt = 0; mt < 2; mt++)
        #pragma unroll
        for (int r = 0; r < 4; r++)
            out[(size_t)(r0 + mt * 16 + q * 4 + r) * HD + wave * 16 + ln] =
                acc2[mt][0][r];
}

// ================= update kernel: OLD (bf16-accum read, fallback) ============
__global__ __launch_bounds__(256) void update_mfma(
    const float* __restrict__ ns, const ushort* __restrict__ S16,
    const unsigned* __restrict__ Mword,
    const ushort* __restrict__ wt1, const float* __restrict__ b1,
    const ushort* __restrict__ wt2, const float* __restrict__ b2,
    float* __restrict__ out)
{
    constexpr int D = 128, PD = D + 8;
    __shared__ __align__(16) ushort Xs[32 * PD];
    __shared__ __align__(16) ushort Hs[32 * PD];

    const int tid = threadIdx.x;
    const int r0  = blockIdx.x * 32;
    const float corr = 1e-16f * __expf(8.f * dec_f32(*Mword));

    for (int lin = tid; lin < 32 * 16; lin += 256) {
        int row = lin >> 4, c8 = (lin & 15) * 8;
        ushort tmp[8];
        if (c8 < 64) {
            ushort raw[8];
            *(uint4*)raw = *(const uint4*)(S16 + (size_t)(r0 + row) * HD + c8);
            #pragma unroll
            for (int j = 0; j < 8; j++)
                tmp[j] = f2bf(0.125f * __logf(bf2f(raw[j]) + corr));
        } else {
            #pragma unroll
            for (int j = 0; j < 8; j++)
                tmp[j] = f2bf(ns[(size_t)(r0 + row) * HD + (c8 - 64) + j]);
        }
        *(uint4*)(Xs + row * PD + c8) = *(uint4*)tmp;
    }
    __syncthreads();

    const int wave = tid >> 6, lane = tid & 63;
    const int q = lane >> 4, ln = lane & 15;

    f32x4 acc[2][2];
    mfma_layer<128, 128, 2, PD>(wt1, b1, Xs, wave, lane, acc);
    #pragma unroll
    for (int mt = 0; mt < 2; mt++)
        #pragma unroll
        for (int nt = 0; nt < 2; nt++)
            #pragma unroll
            for (int r = 0; r < 4; r++)
                Hs[(mt * 16 + q * 4 + r) * PD + wave * 32 + nt * 16 + ln] =
                    f2bf(fmaxf(acc[mt][nt][r], 0.f));
    __syncthreads();

    f32x4 acc2[2][1];
    mfma_layer<128, 64, 1, PD>(wt2, b2, Hs, wave, lane, acc2);
    #pragma unroll
    for (int mt = 0; mt < 2; mt++)
        #pragma unroll
        for (int r = 0; r < 4; r++)
            out[(size_t)(r0 + mt * 16 + q * 4 + r) * HD + wave * 16 + ln] =
                acc2[mt][0][r];
}

// ================= host =====================================================
extern "C" void kernel_launch(void* const* d_in, const int* in_sizes, int n_in,
                              void* d_out, int out_size, void* d_ws, size_t ws_size,
                              hipStream_t stream)
{
    const float* ns   = (const float*)d_in[0];
    const int*   idx0 = (const int*)d_in[1];
    const int*   idx1 = (const int*)d_in[2];
    const int*   idx2 = (const int*)d_in[3];
    const float* W[8] = { (const float*)d_in[4],  (const float*)d_in[6],
                          (const float*)d_in[8],  (const float*)d_in[10],
                          (const float*)d_in[12], (const float*)d_in[14],
                          (const float*)d_in[16], (const float*)d_in[18] };
    const float* B[8] = { (const float*)d_in[5],  (const float*)d_in[7],
                          (const float*)d_in[9],  (const float*)d_in[11],
                          (const float*)d_in[13], (const float*)d_in[15],
                          (const float*)d_in[17], (const float*)d_in[19] };
    static const int DIN[8]  = {128,128,128,128,192,192,128,128};
    static const int DOUT[8] = {128,128,128,128,192,192,128, 64};

    const int n0f = in_sizes[1];          // 600000 flat ints
    const int n1f = in_sizes[2];          // 600000
    const int n2f = in_sizes[3];          // 600000
    const int TOT = n0f + n1f + n2f;      // 1,800,000
    const int T0 = n0f / 2, T1 = n1f / 2, T2 = n2f / 3;

    size_t wtot = 0;
    for (int m = 0; m < 8; m++) wtot += (size_t)DIN[m] * DOUT[m];   // 360,448

    // ---- new-path workspace layout ----
    size_t oO     = 0;
    size_t oNs    = oO  + (size_t)TOT * HD * 2;                     // O2: 230.4 MB
    size_t oWT    = oNs + (size_t)NS_ELEMS * 2;                     // ns16: 25.6 MB
    size_t oPerm  = oWT + ((wtot * 2 + 255) & ~(size_t)255);
    size_t oStart = oPerm + (((size_t)TOT * 4 + 255) & ~(size_t)255);
    size_t oOff   = oStart + (((size_t)(NNODES + 1) * 4 + 255) & ~(size_t)255);
    size_t oPart  = oOff + (size_t)NNODES * 4;
    size_t oCnt   = oPart + 4096;
    size_t oMw    = oCnt + (size_t)NNODES * 4;
    size_t NEED   = oMw + 64;

    if (ws_size >= NEED) {
        // ================= perm / streaming pipelined path =================
        ushort*   O2    = (ushort*)d_ws;
        ushort*   ns16  = (ushort*)((char*)d_ws + oNs);
        ushort*   WTb   = (ushort*)((char*)d_ws + oWT);
        int*      perm  = (int*)((char*)d_ws + oPerm);
        int*      start = (int*)((char*)d_ws + oStart);
        int*      offp  = (int*)((char*)d_ws + oOff);
        int*      part  = (int*)((char*)d_ws + oPart);
        int*      cnt   = (int*)((char*)d_ws + oCnt);
        unsigned* Mw    = (unsigned*)((char*)d_ws + oMw);

        PrepArgs pa;
        int total = NS_ELEMS;
        ushort* wt[8];
        {
            ushort* p = WTb;
            for (int m = 0; m < 8; m++) {
                pa.src[m] = W[m];
                pa.dst[m] = p;  wt[m] = p;
                pa.din[m] = DIN[m]; pa.dout[m] = DOUT[m];
                pa.nelem[m] = DIN[m] * DOUT[m];
                p += pa.nelem[m];
                total += pa.nelem[m];
            }
        }

        hipMemsetAsync((char*)d_ws + oCnt, 0, (size_t)NNODES * 4 + 64, stream);
        prep_kernel<<<4096, 256, 0, stream>>>(ns, ns16, pa, total);

        const int NB   = (NNODES + 255) / 256;
        const int gTOT = (TOT + 255) / 256;
        hist_kernel<<<gTOT, 256, 0, stream>>>(idx0, idx1, idx2, n0f, n0f + n1f, TOT, cnt);
        scan1_kernel<<<NB, 256, 0, stream>>>(cnt, start, part, NNODES);
        scan2_kernel<<<1, 1024, 0, stream>>>(part, NB);
        scan3_kernel<<<NB, 256, 0, stream>>>(start, offp, part, NNODES, TOT);
        fill_perm<<<gTOT, 256, 0, stream>>>(idx0, idx1, idx2, n0f, n0f + n1f, TOT, offp, perm);

        // persistent pipelined rel kernels
        int nt0 = T0 / 32, nt1 = T1 / 32, nt2 = T2 / 32;
        int g2a = nt0 < 1536 ? nt0 : 1536;      // 6 blocks/CU (LDS 26.6 KB)
        int g2b = nt1 < 1536 ? nt1 : 1536;
        int g3  = nt2 < 1024 ? nt2 : 1024;      // 4 blocks/CU (LDS 39.2 KB)

        rel_mfma_pp<2><<<g2a, 256, 0, stream>>>(
            ns16, idx0, perm, wt[0], B[0], wt[1], B[1], O2, Mw, nt0);
        rel_mfma_pp<2><<<g2b, 256, 0, stream>>>(
            ns16, idx1, perm + n0f, wt[2], B[2], wt[3], B[3], O2, Mw, nt1);
        rel_mfma_pp<3><<<g3, 256, 0, stream>>>(
            ns16, idx2, perm + n0f + n1f, wt[4], B[4], wt[5], B[5], O2, Mw, nt2);

        update_lin<<<NNODES / 32, 256, 0, stream>>>(
            ns, O2, start, Mw, wt[6], B[6], wt[7], B[7], (float*)d_out);
    } else {
        // ================= fallback: atomic path =================
        ushort*   S16  = (ushort*)d_ws;
        size_t    offM = (size_t)NNODES * HD * sizeof(ushort);
        unsigned* Mw   = (unsigned*)((char*)d_ws + offM);
        ushort*   ns16 = (ushort*)((char*)d_ws + offM + 64);
        ushort*   WTb  = ns16 + (size_t)NS_ELEMS;

        PrepArgs pa;
        int total = NS_ELEMS;
        ushort* wt[8];
        {
            ushort* p = WTb;
            for (int m = 0; m < 8; m++) {
                pa.src[m] = W[m];
                pa.dst[m] = p;  wt[m] = p;
                pa.din[m] = DIN[m]; pa.dout[m] = DOUT[m];
                pa.nelem[m] = DIN[m] * DOUT[m];
                p += pa.nelem[m];
                total += pa.nelem[m];
            }
        }

        hipMemsetAsync(d_ws, 0, offM + 64, stream);
        prep_kernel<<<4096, 256, 0, stream>>>(ns, ns16, pa, total);

        rel_mfma<2><<<T0 / 32, 256, 0, stream>>>(ns16, idx0, wt[0], B[0], wt[1], B[1], S16, Mw);
        rel_mfma<2><<<T1 / 32, 256, 0, stream>>>(ns16, idx1, wt[2], B[2], wt[3], B[3], S16, Mw);
        rel_mfma<3><<<T2 / 32, 256, 0, stream>>>(ns16, idx2, wt[4], B[4], wt[5], B[5], S16, Mw);
        update_mfma<<<NNODES / 32, 256, 0, stream>>>(ns, S16, Mw, wt[6], B[6], wt[7], B[7],
                                                     (float*)d_out);
    }
}